// Round 1
// baseline (38.337 us; speedup 1.0000x reference)
//
#include <hip/hip_runtime.h>

// Problem constants (from reference)
#define WSZ   8      // window size
#define BINS  256
#define NB    8      // batch
#define NC    3      // channels
#define HH    1024
#define WW    1024
#define NH    (HH / WSZ)   // 128 window rows
#define NW    (WW / WSZ)   // 128 window cols

// Tiling: each block owns one window-row x 16 window-columns
constexpr int WIN_T   = 16;               // windows per block
constexpr int COLS    = WIN_T * WSZ;      // 128 columns of x per block
constexpr int TILES   = NW / WIN_T;       // 8 column tiles per window row
constexpr int THREADS = 512;
constexpr int N_F4    = (NB * NC * WSZ * COLS) / 4;  // 6144 float4 loads per block
constexpr int HIST_N  = WIN_T * BINS;                // 4096 counters (16 KiB)

__global__ __launch_bounds__(THREADS)
void ComputeHistograms_71159018160701_kernel(const float* __restrict__ x,
                                             float* __restrict__ out) {
    __shared__ unsigned int hist[HIST_N];

    const int bid  = blockIdx.x;          // 0 .. NH*TILES-1
    const int irow = bid / TILES;         // window row 0..127
    const int tile = bid % TILES;         // column tile 0..7
    const int tid  = threadIdx.x;

    // zero LDS histograms
    for (int k = tid; k < HIST_N; k += THREADS) hist[k] = 0u;
    __syncthreads();

    // Accumulate. Each float4 = 4 consecutive elements, 4-aligned, so it
    // stays inside one 8-wide window.
    const int col0 = tile * COLS;
    for (int k = tid; k < N_F4; k += THREADS) {
        const int seg  = k >> 5;          // (b*NC + c)*WSZ + r ; 32 float4/segment
        const int off4 = k & 31;          // float4 index within the 128-col segment
        const int bc   = seg >> 3;        // b*NC + c
        const int r    = seg & 7;
        const float4 v = *reinterpret_cast<const float4*>(
            x + ((size_t)bc * HH + (size_t)irow * WSZ + r) * WW + col0 + off4 * 4);
        unsigned int* hw = &hist[(off4 >> 1) * BINS];  // local window 0..15
        #pragma unroll
        for (int e = 0; e < 4; ++e) {
            const float xv = (e == 0) ? v.x : (e == 1) ? v.y : (e == 2) ? v.z : v.w;
            // torch.histc semantics: floor(x*BINS); x==MAX -> last bin;
            // out-of-range dropped. scale=256 is pow2 so the mul is exact.
            int b = (int)floorf(xv * 256.0f);
            if (xv == 1.0f) b = BINS - 1;
            b = min(max(b, 0), BINS - 1);
            if (xv >= 0.0f && xv <= 1.0f) atomicAdd(&hw[b], 1u);
        }
    }
    __syncthreads();

    // Broadcast-write: this block's 4096 counts go to 8 contiguous 16 KiB
    // regions, one per batch slot. float4 stores, fully coalesced.
    for (int k = tid; k < HIST_N / 4; k += THREADS) {   // 1024 groups, 2 iters
        const uint4 cv = *reinterpret_cast<const uint4*>(&hist[k * 4]);
        const float4 fv = make_float4((float)cv.x, (float)cv.y,
                                      (float)cv.z, (float)cv.w);
        #pragma unroll
        for (int b = 0; b < NB; ++b) {
            const size_t base =
                (((size_t)b * NH + irow) * NW + (size_t)tile * WIN_T) * BINS;
            *reinterpret_cast<float4*>(out + base + k * 4) = fv;
        }
    }
}

extern "C" void kernel_launch(void* const* d_in, const int* in_sizes, int n_in,
                              void* d_out, int out_size, void* d_ws, size_t ws_size,
                              hipStream_t stream) {
    const float* x = (const float*)d_in[0];
    float* out = (float*)d_out;
    ComputeHistograms_71159018160701_kernel<<<dim3(NH * TILES), dim3(THREADS), 0,
                                              stream>>>(x, out);
}